// Round 3
// baseline (174.109 us; speedup 1.0000x reference)
//
#include <hip/hip_runtime.h>
#include <hip/hip_bf16.h>

typedef __attribute__((ext_vector_type(8))) short bf16x8;
typedef __attribute__((ext_vector_type(4))) float f32x4;

#define NB 32
#define NS 512
#define ND 1024

__device__ __forceinline__ unsigned short f2bf(float f) {
  unsigned int u = __float_as_uint(f);
  u = (u + 0x7FFFu + ((u >> 16) & 1u)) >> 16;  // RNE
  return (unsigned short)u;
}

// ---------- normalized embeddings -> bf16; blocks 0..31 also do aspect ----------
__global__ __launch_bounds__(256)
void enormbf_fused_kernel(const float* __restrict__ emb,
                          unsigned short* __restrict__ eN,
                          const float* __restrict__ aspect,
                          unsigned short* __restrict__ a_n) {
  int wave = threadIdx.x >> 6, lane = threadIdx.x & 63;
  size_t row = (size_t)blockIdx.x * 4 + wave;  // 0..16383
  const float4* p = (const float4*)(emb + row * ND);
  float4 v[4];
  float s = 0.f;
#pragma unroll
  for (int j = 0; j < 4; ++j) {
    v[j] = p[lane + 64 * j];
    s += v[j].x * v[j].x + v[j].y * v[j].y + v[j].z * v[j].z + v[j].w * v[j].w;
  }
#pragma unroll
  for (int off = 32; off >= 1; off >>= 1) s += __shfl_xor(s, off);
  float inv = (s > 0.f) ? (1.f / sqrtf(s)) : 0.f;
  ushort4* o = (ushort4*)(eN + row * ND);
#pragma unroll
  for (int j = 0; j < 4; ++j) {
    ushort4 u;
    u.x = f2bf(v[j].x * inv); u.y = f2bf(v[j].y * inv);
    u.z = f2bf(v[j].z * inv); u.w = f2bf(v[j].w * inv);
    o[lane + 64 * j] = u;
  }

  if (blockIdx.x < NB) {  // fused anorm for batch b = blockIdx.x
    int b = blockIdx.x;
    int t = threadIdx.x;
    const float4* pa = (const float4*)(aspect + (size_t)b * ND);
    float4 va = pa[t];
    float sa = va.x * va.x + va.y * va.y + va.z * va.z + va.w * va.w;
#pragma unroll
    for (int off = 32; off >= 1; off >>= 1) sa += __shfl_down(sa, off);
    __shared__ float red[4];
    if ((t & 63) == 0) red[t >> 6] = sa;
    __syncthreads();
    float tot = red[0] + red[1] + red[2] + red[3];
    float inva = (tot > 0.f) ? (1.f / sqrtf(tot)) : 0.f;
    ushort4 u;
    u.x = f2bf(va.x * inva); u.y = f2bf(va.y * inva);
    u.z = f2bf(va.z * inva); u.w = f2bf(va.w * inva);
    ((ushort4*)(a_n + (size_t)b * ND))[t] = u;
  }
}

// ---------- GEMM v6: A direct global->VGPR (no A-LDS, no global_load_lds,
// ZERO K-loop barriers). 256-thread blocks (4 waves), tile 128x256, 2 blk/CU.
// Waves free-run; compiler emits per-register vmcnt/lgkmcnt waits. B comes
// from the read-only circulant `copies` LDS window (one prologue barrier).
// A fragment (lane l16,q): row rb*16+l16, 16B at k-col q*8 -> one
// global_load_dwordx4; 4 q-groups x 2 kk consume full 128B lines; the 4
// col-waves re-hit the same lines in L1 (16 KiB unique/tile, 4x reuse).
__global__ __launch_bounds__(256, 2)
void corr_gemm6_kernel(const unsigned short* __restrict__ eN,
                       const unsigned short* __restrict__ a_n,
                       float* __restrict__ out) {
  __shared__ __align__(16) unsigned short copies[8 * 1288];

  const int b = blockIdx.x, mt = blockIdx.y, nt = blockIdx.z;
  const int n0 = nt * 256, m0 = mt * 128;
  const int tid = threadIdx.x;

  const int lane = tid & 63, wn = tid >> 6;   // 4 waves = 4 col-quarters
  const int q = lane >> 4, l16 = lane & 15;
  const int mx = l16 & 7;

  // ---- prologue: build circulant copies window (8 x 1280), one barrier ----
  {
    const unsigned short* an = a_n + (size_t)b * ND;
    const int p = tid & 7;
    const int x0 = (tid >> 3) * 40;                 // 32 threads/copy x 40 = 1280
    const int base = (768 - n0 + p) & 1023;
#pragma unroll
    for (int j = 0; j < 40; j += 4) {
      ushort4 u;
      u.x = an[(base + x0 + j + 0) & 1023];
      u.y = an[(base + x0 + j + 1) & 1023];
      u.z = an[(base + x0 + j + 2) & 1023];
      u.w = an[(base + x0 + j + 3) & 1023];
      *(ushort4*)&copies[p * 1288 + x0 + j] = u;
    }
  }
  __syncthreads();   // copies visible; NO further barriers

  // B read base: addr = copies + pB*1287 + idx; idx = kt*64 + kk*32 + 8q + 256 - n_local
  const int pB = (8 - mx) & 7;
  const unsigned short* Bp = copies + pB * 1287 + (256 + 8 * q - wn * 64 - l16);

  // A per-lane base: row (m0 + l16), k-col q*8 ; frag(rb,kk,kt) = +rb*16*ND + kt*64 + kk*32
  const unsigned short* Abase = eN + ((size_t)b * NS + m0 + l16) * ND + q * 8;

  f32x4 acc[8][4];
#pragma unroll
  for (int i = 0; i < 8; ++i)
#pragma unroll
    for (int j = 0; j < 4; ++j)
      acc[i][j] = (f32x4){0.f, 0.f, 0.f, 0.f};

  bf16x8 a0[4], a1[4], bfr[4][2];

#define ISSUE_A(DST, RB, KTT)                                       \
  do {                                                              \
    const unsigned short* _p = Abase + (size_t)(RB) * (16 * ND) + (KTT) * 64; \
    DST[0] = *(const bf16x8*)(_p);                                  \
    DST[1] = *(const bf16x8*)(_p + 32);                             \
    DST[2] = *(const bf16x8*)(_p + 16 * ND);                        \
    DST[3] = *(const bf16x8*)(_p + 16 * ND + 32);                   \
  } while (0)

#define LOAD_B(KTT)                                                 \
  do {                                                              \
    const unsigned short* Bt = Bp + (KTT) * 64;                     \
    _Pragma("unroll")                                               \
    for (int n = 0; n < 4; ++n) {                                   \
      bfr[n][0] = *(const bf16x8*)(Bt - n * 16);                    \
      bfr[n][1] = *(const bf16x8*)(Bt + 32 - n * 16);               \
    }                                                               \
  } while (0)

#define MFMA_PH(PH, CS)                                                                       \
  do {                                                                                        \
    __builtin_amdgcn_s_setprio(1);                                                            \
    _Pragma("unroll")                                                                         \
    for (int n = 0; n < 4; ++n) {                                                             \
      acc[2*(PH)][n]   = __builtin_amdgcn_mfma_f32_16x16x32_bf16(CS[0], bfr[n][0], acc[2*(PH)][n],   0, 0, 0); \
      acc[2*(PH)][n]   = __builtin_amdgcn_mfma_f32_16x16x32_bf16(CS[1], bfr[n][1], acc[2*(PH)][n],   0, 0, 0); \
      acc[2*(PH)+1][n] = __builtin_amdgcn_mfma_f32_16x16x32_bf16(CS[2], bfr[n][0], acc[2*(PH)+1][n], 0, 0, 0); \
      acc[2*(PH)+1][n] = __builtin_amdgcn_mfma_f32_16x16x32_bf16(CS[3], bfr[n][1], acc[2*(PH)+1][n], 0, 0, 0); \
    }                                                                                         \
    __builtin_amdgcn_s_setprio(0);                                                            \
  } while (0)

  // prime: phase-0 A frags + B of tile 0 in flight
  ISSUE_A(a0, 0, 0);
  LOAD_B(0);

#pragma unroll 1
  for (int kt = 0; kt < 16; ++kt) {
    ISSUE_A(a1, 2, kt);          // rb 2,3 in flight under ph0 MFMA
    MFMA_PH(0, a0);
    ISSUE_A(a0, 4, kt);
    MFMA_PH(1, a1);
    ISSUE_A(a1, 6, kt);
    MFMA_PH(2, a0);
    const int ktn = (kt < 15) ? kt + 1 : 15;   // clamp: avoid OOB, redundant reload on last
    ISSUE_A(a0, 0, ktn);
    MFMA_PH(3, a1);
    __builtin_amdgcn_sched_barrier(0);  // pin B reload after ph3's reads (reg reuse, no dbuf)
    LOAD_B(ktn);
  }
#undef MFMA_PH
#undef LOAD_B
#undef ISSUE_A

  // epilogue: C/D layout col=lane&15, row=(lane>>4)*4+reg
  float* outB = out + ((size_t)b * NS + m0) * ND + n0;
#pragma unroll
  for (int i = 0; i < 8; ++i) {
#pragma unroll
    for (int rg = 0; rg < 4; ++rg) {
      int r = i * 16 + q * 4 + rg;
      float* orow = outB + (size_t)r * ND + wn * 64 + l16;
#pragma unroll
      for (int n = 0; n < 4; ++n)
        orow[n * 16] = acc[i][n][rg];
    }
  }
}

// ---------- fallback path (round-1 kernels) in case ws is small ----------
__global__ void anorm_kernel(const float* __restrict__ aspect,
                             unsigned short* __restrict__ a_n) {
  int b = blockIdx.x;
  int t = threadIdx.x;
  const float4* p = (const float4*)(aspect + (size_t)b * ND);
  float4 v = p[t];
  float s = v.x * v.x + v.y * v.y + v.z * v.z + v.w * v.w;
#pragma unroll
  for (int off = 32; off >= 1; off >>= 1) s += __shfl_down(s, off);
  __shared__ float red[4];
  if ((t & 63) == 0) red[t >> 6] = s;
  __syncthreads();
  float tot = red[0] + red[1] + red[2] + red[3];
  float inv = (tot > 0.f) ? (1.f / sqrtf(tot)) : 0.f;
  ushort4 u;
  u.x = f2bf(v.x * inv); u.y = f2bf(v.y * inv);
  u.z = f2bf(v.z * inv); u.w = f2bf(v.w * inv);
  ((ushort4*)(a_n + (size_t)b * ND))[t] = u;
}

__global__ void enorm_kernel(const float* __restrict__ emb,
                             float* __restrict__ inv_norm) {
  int wave = threadIdx.x >> 6;
  int lane = threadIdx.x & 63;
  int row = blockIdx.x * 4 + wave;
  const float4* p = (const float4*)(emb + (size_t)row * ND);
  float s = 0.f;
#pragma unroll
  for (int j = 0; j < 4; ++j) {
    float4 v = p[lane + 64 * j];
    s += v.x * v.x + v.y * v.y + v.z * v.z + v.w * v.w;
  }
#pragma unroll
  for (int off = 32; off >= 1; off >>= 1) s += __shfl_down(s, off);
  if (lane == 0) inv_norm[row] = (s > 0.f) ? (1.f / sqrtf(s)) : 0.f;
}

__global__ __launch_bounds__(256)
void corr_gemm_kernel(const float* __restrict__ emb,
                      const float* __restrict__ inv_norm,
                      const unsigned short* __restrict__ a_n,
                      float* __restrict__ out) {
  __shared__ unsigned short copies[8][2056];
  __shared__ unsigned short Atile[128][40];

  const int nt = blockIdx.x, mt = blockIdx.y, b = blockIdx.z;
  const int n0 = nt * 128, m0 = mt * 128;
  const int t = threadIdx.x;

  {
    const unsigned short* an = a_n + (size_t)b * ND;
    int p = t & 7;
    int x0 = (t >> 3) * 64;
#pragma unroll
    for (int j = 0; j < 64; j += 4) {
      ushort4 u;
      u.x = an[(x0 + j + 0 + p) & 1023];
      u.y = an[(x0 + j + 1 + p) & 1023];
      u.z = an[(x0 + j + 2 + p) & 1023];
      u.w = an[(x0 + j + 3 + p) & 1023];
      *(ushort4*)&copies[p][x0 + j] = u;
    }
  }

  const int ar = t >> 3;
  const int ac = (t & 7) * 4;
  float invn[4];
#pragma unroll
  for (int w = 0; w < 4; ++w)
    invn[w] = inv_norm[b * NS + m0 + ar + 32 * w];

  const int lane = t & 63;
  const int wv = t >> 6;
  const int wm = wv >> 1, wn = wv & 1;
  const int q = lane >> 4, l16 = lane & 15;

  f32x4 acc[4][4];
#pragma unroll
  for (int i = 0; i < 4; ++i)
#pragma unroll
    for (int j = 0; j < 4; ++j)
      acc[i][j] = (f32x4){0.f, 0.f, 0.f, 0.f};

  const float* embB = emb + ((size_t)b * NS + m0) * ND;

  for (int k0 = 0; k0 < ND; k0 += 32) {
    __syncthreads();
#pragma unroll
    for (int w = 0; w < 4; ++w) {
      int r = ar + 32 * w;
      float4 v = *(const float4*)(embB + (size_t)r * ND + k0 + ac);
      float in = invn[w];
      ushort4 u;
      u.x = f2bf(v.x * in); u.y = f2bf(v.y * in);
      u.z = f2bf(v.z * in); u.w = f2bf(v.w * in);
      *(ushort4*)&Atile[r][ac] = u;
    }
    __syncthreads();

    bf16x8 af[4], bfr[4];
#pragma unroll
    for (int r = 0; r < 4; ++r) {
      int m = wm * 64 + r * 16 + l16;
      af[r] = *(const bf16x8*)&Atile[m][q * 8];
    }
#pragma unroll
    for (int r = 0; r < 4; ++r) {
      int ng = n0 + wn * 64 + r * 16 + l16;
      int e0 = k0 + 8 * q - ng + 1024;
      int p = e0 & 7;
      bfr[r] = *(const bf16x8*)&copies[p][e0 - p];
    }
#pragma unroll
    for (int i = 0; i < 4; ++i)
#pragma unroll
      for (int j = 0; j < 4; ++j)
        acc[i][j] = __builtin_amdgcn_mfma_f32_16x16x32_bf16(af[i], bfr[j], acc[i][j], 0, 0, 0);
  }

  float* outB = out + ((size_t)b * NS + m0) * ND + n0;
#pragma unroll
  for (int i = 0; i < 4; ++i) {
#pragma unroll
    for (int rg = 0; rg < 4; ++rg) {
      int s = wm * 64 + i * 16 + q * 4 + rg;
      float* orow = outB + (size_t)s * ND + wn * 64 + l16;
#pragma unroll
      for (int j = 0; j < 4; ++j)
        orow[j * 16] = acc[i][j][rg];
    }
  }
}

extern "C" void kernel_launch(void* const* d_in, const int* in_sizes, int n_in,
                              void* d_out, int out_size, void* d_ws, size_t ws_size,
                              hipStream_t stream) {
  const float* emb = (const float*)d_in[0];
  const float* aspect = (const float*)d_in[1];
  float* out = (float*)d_out;

  const size_t need = 65536 + (size_t)NB * NS * ND * 2;  // a_n + eN(bf16)

  if (ws_size >= need) {
    unsigned short* a_n = (unsigned short*)d_ws;
    unsigned short* eN = (unsigned short*)((char*)d_ws + 65536);
    enormbf_fused_kernel<<<4096, 256, 0, stream>>>(emb, eN, aspect, a_n);
    // grid (b, mt, nt): flat id = b + 32*mt + 128*nt -> all 16 tiles of batch b
    // land on XCD b%8 -> eN panel L2 reuse across mt/nt siblings.
    corr_gemm6_kernel<<<dim3(NB, 4, 4), 256, 0, stream>>>(eN, a_n, out);
  } else {
    float* inv_norm = (float*)d_ws;
    unsigned short* a_n = (unsigned short*)((char*)d_ws + 65536);
    enorm_kernel<<<4096, 256, 0, stream>>>(emb, inv_norm);
    anorm_kernel<<<NB, 256, 0, stream>>>(aspect, a_n);
    corr_gemm_kernel<<<dim3(8, 4, NB), 256, 0, stream>>>(emb, inv_norm, a_n, out);
  }
}

// Round 5
// 136.925 us; speedup vs baseline: 1.2716x; 1.2716x over previous
//
#include <hip/hip_runtime.h>
#include <hip/hip_bf16.h>

typedef __attribute__((ext_vector_type(8))) short bf16x8;
typedef __attribute__((ext_vector_type(4))) float f32x4;

#define NB 32
#define NS 512
#define ND 1024

__device__ __forceinline__ unsigned short f2bf(float f) {
  unsigned int u = __float_as_uint(f);
  u = (u + 0x7FFFu + ((u >> 16) & 1u)) >> 16;  // RNE
  return (unsigned short)u;
}

// ---------- normalized embeddings -> bf16; blocks 0..31 also do aspect ----------
__global__ __launch_bounds__(256)
void enormbf_fused_kernel(const float* __restrict__ emb,
                          unsigned short* __restrict__ eN,
                          const float* __restrict__ aspect,
                          unsigned short* __restrict__ a_n) {
  int wave = threadIdx.x >> 6, lane = threadIdx.x & 63;
  size_t row = (size_t)blockIdx.x * 4 + wave;  // 0..16383
  const float4* p = (const float4*)(emb + row * ND);
  float4 v[4];
  float s = 0.f;
#pragma unroll
  for (int j = 0; j < 4; ++j) {
    v[j] = p[lane + 64 * j];
    s += v[j].x * v[j].x + v[j].y * v[j].y + v[j].z * v[j].z + v[j].w * v[j].w;
  }
#pragma unroll
  for (int off = 32; off >= 1; off >>= 1) s += __shfl_xor(s, off);
  float inv = (s > 0.f) ? (1.f / sqrtf(s)) : 0.f;
  ushort4* o = (ushort4*)(eN + row * ND);
#pragma unroll
  for (int j = 0; j < 4; ++j) {
    ushort4 u;
    u.x = f2bf(v[j].x * inv); u.y = f2bf(v[j].y * inv);
    u.z = f2bf(v[j].z * inv); u.w = f2bf(v[j].w * inv);
    o[lane + 64 * j] = u;
  }

  if (blockIdx.x < NB) {  // fused anorm for batch b = blockIdx.x
    int b = blockIdx.x;
    int t = threadIdx.x;
    const float4* pa = (const float4*)(aspect + (size_t)b * ND);
    float4 va = pa[t];
    float sa = va.x * va.x + va.y * va.y + va.z * va.z + va.w * va.w;
#pragma unroll
    for (int off = 32; off >= 1; off >>= 1) sa += __shfl_down(sa, off);
    __shared__ float red[4];
    if ((t & 63) == 0) red[t >> 6] = sa;
    __syncthreads();
    float tot = red[0] + red[1] + red[2] + red[3];
    float inva = (tot > 0.f) ? (1.f / sqrtf(tot)) : 0.f;
    ushort4 u;
    u.x = f2bf(va.x * inva); u.y = f2bf(va.y * inva);
    u.z = f2bf(va.z * inva); u.w = f2bf(va.w * inva);
    ((ushort4*)(a_n + (size_t)b * ND))[t] = u;
  }
}

// ---------- GEMM v8: 128x256 tile, 4 waves (1m x 4n), ring-3 A via
// global_load_lds, 2 blocks/CU (LDS 68.1 KiB). ONE barrier per K-tile;
// counted lgkmcnt(4) operand pipelining; counted vmcnt(4) at tile seam.
// Desynced sibling blocks overlap epilogue/barrier stalls with MFMA.
__global__ __launch_bounds__(256, 2)
void corr_gemm8_kernel(const unsigned short* __restrict__ eN,
                       const unsigned short* __restrict__ a_n,
                       float* __restrict__ out) {
  __shared__ __align__(16) unsigned short Alds[3 * 8192];    // 3 x 128 x 64
  __shared__ __align__(16) unsigned short copies[8 * 1288];  // circulant window

  const int b = blockIdx.x, mt = blockIdx.y, nt = blockIdx.z;
  const int n0 = nt * 256, m0 = mt * 128;
  const int tid = threadIdx.x;

  const int lane = tid & 63, wn = tid >> 6;  // 4 waves = 4 col-quarters (128x64 each)
  const int q = lane >> 4, l16 = lane & 15;
  const int mx = l16 & 7;
  const int s00 = (q ^ mx) * 8;              // chunk q     (kk=0)
  const int s01 = ((4 + q) ^ mx) * 8;        // chunk 4+q   (kk=1)
  const int arow = l16 * 64;

  // B read base: addr = copies + pB*1287 + idx; idx = kt*64 + kk*32 + 8q + 256 - n_local
  const int pB = (8 - mx) & 7;
  const unsigned short* Bp = copies + pB * 1287 + (256 + 8 * q - wn * 64 - l16);

  // A staging source (inverse chunk swizzle); LDS dst = slot + tid*16 + j*4096
  const unsigned short* gstage =
      eN + ((size_t)b * NS + m0 + (tid >> 3)) * ND + (size_t)(((tid & 7) ^ ((tid >> 3) & 7)) * 8);
  char* ldsAbase = (char*)Alds;

  // ---- prologue 1: gather a_n window into regs (older vmem, drained by writes) ----
  unsigned short av[40];
  {
    const unsigned short* an = a_n + (size_t)b * ND;
    const int p = tid & 7;
    const int x0 = (tid >> 3) * 40;  // 32 threads/copy x 40 = 1280
    const int base = (768 - n0 + p) & 1023;
#pragma unroll
    for (int j = 0; j < 40; ++j) av[j] = an[(base + x0 + j) & 1023];
  }

  // ---- prologue 2: stage tiles 0,1 into slots 0,1 (8 gloads, stay in flight) ----
#pragma unroll
  for (int j = 0; j < 4; ++j)
    __builtin_amdgcn_global_load_lds(
        (const __attribute__((address_space(1))) void*)(gstage + (size_t)j * 32 * ND),
        (__attribute__((address_space(3))) void*)(ldsAbase + (size_t)tid * 16 + j * 4096),
        16, 0, 0);
#pragma unroll
  for (int j = 0; j < 4; ++j)
    __builtin_amdgcn_global_load_lds(
        (const __attribute__((address_space(1))) void*)(gstage + (size_t)j * 32 * ND + 64),
        (__attribute__((address_space(3))) void*)(ldsAbase + 16384 + (size_t)tid * 16 + j * 4096),
        16, 0, 0);

  // ---- prologue 3: write copies (compiler waits drain av-loads, keep stages) ----
  {
    const int p = tid & 7;
    const int x0 = (tid >> 3) * 40;
#pragma unroll
    for (int j = 0; j < 40; ++j) copies[p * 1288 + x0 + j] = av[j];
  }

  f32x4 acc[8][4];
#pragma unroll
  for (int i = 0; i < 8; ++i)
#pragma unroll
    for (int j = 0; j < 4; ++j)
      acc[i][j] = (f32x4){0.f, 0.f, 0.f, 0.f};

  asm volatile("s_waitcnt lgkmcnt(0)" ::: "memory");  // copies writes done (this wave)
  __builtin_amdgcn_sched_barrier(0);
  __builtin_amdgcn_s_barrier();                       // copies visible block-wide
  asm volatile("s_waitcnt vmcnt(4)" ::: "memory");    // slot0 retired; slot1 in flight
  __builtin_amdgcn_sched_barrier(0);
  __builtin_amdgcn_s_barrier();                       // slot0 ready for all waves

  bf16x8 a0[4], a1[4], bfr[4][2];

#define ISSUE_A(DST, BASE, PHN)                                          \
  do {                                                                   \
    DST[0] = *(const bf16x8*)&(BASE)[arow + (PHN) * 2048 + s00];         \
    DST[1] = *(const bf16x8*)&(BASE)[arow + (PHN) * 2048 + s01];         \
    DST[2] = *(const bf16x8*)&(BASE)[arow + (PHN) * 2048 + 1024 + s00];  \
    DST[3] = *(const bf16x8*)&(BASE)[arow + (PHN) * 2048 + 1024 + s01];  \
  } while (0)

#define STAGE4(SLOT, KTT)                                                              \
  do {                                                                                 \
    const unsigned short* sg_ = gstage + (size_t)(KTT) * 64;                           \
    char* dl_ = ldsAbase + (SLOT) * 16384 + (size_t)tid * 16;                          \
    _Pragma("unroll")                                                                  \
    for (int j = 0; j < 4; ++j)                                                        \
      __builtin_amdgcn_global_load_lds(                                                \
          (const __attribute__((address_space(1))) void*)(sg_ + (size_t)j * 32 * ND),  \
          (__attribute__((address_space(3))) void*)(dl_ + j * 4096), 16, 0, 0);        \
  } while (0)

#define LOAD_B(KTT)                                                 \
  do {                                                              \
    const unsigned short* Bt = Bp + (KTT) * 64;                     \
    _Pragma("unroll")                                               \
    for (int n = 0; n < 4; ++n) {                                   \
      bfr[n][0] = *(const bf16x8*)(Bt - n * 16);                    \
      bfr[n][1] = *(const bf16x8*)(Bt + 32 - n * 16);               \
    }                                                               \
  } while (0)

#define MFMA_PH(PH, CS)                                                                       \
  do {                                                                                        \
    __builtin_amdgcn_s_setprio(1);                                                            \
    _Pragma("unroll")                                                                         \
    for (int n = 0; n < 4; ++n) {                                                             \
      acc[2*(PH)][n]   = __builtin_amdgcn_mfma_f32_16x16x32_bf16(CS[0], bfr[n][0], acc[2*(PH)][n],   0, 0, 0); \
      acc[2*(PH)][n]   = __builtin_amdgcn_mfma_f32_16x16x32_bf16(CS[1], bfr[n][1], acc[2*(PH)][n],   0, 0, 0); \
      acc[2*(PH)+1][n] = __builtin_amdgcn_mfma_f32_16x16x32_bf16(CS[2], bfr[n][0], acc[2*(PH)+1][n], 0, 0, 0); \
      acc[2*(PH)+1][n] = __builtin_amdgcn_mfma_f32_16x16x32_bf16(CS[3], bfr[n][1], acc[2*(PH)+1][n], 0, 0, 0); \
    }                                                                                         \
    __builtin_amdgcn_s_setprio(0);                                                            \
  } while (0)

  int c0 = 0, c1 = 1, c2 = 2;

#pragma unroll 1
  for (int kt = 0; kt < 16; ++kt) {
    const unsigned short* At = Alds + c0 * 8192;

    if (kt + 2 < 16) STAGE4(c2, kt + 2);     // vmem issue early (ring slot c2)

    ISSUE_A(a0, At, 0);                       // 4 lgkm
    LOAD_B(kt);                               // 8 lgkm
    ISSUE_A(a1, At, 1);                       // 4 lgkm  -> 16 outstanding
    asm volatile("s_waitcnt lgkmcnt(4)" ::: "memory");  // a0+B ready; a1 in flight
    __builtin_amdgcn_sched_barrier(0);
    MFMA_PH(0, a0);

    ISSUE_A(a0, At, 2);
    asm volatile("s_waitcnt lgkmcnt(4)" ::: "memory");  // a1 ready; a0(ph2) in flight
    __builtin_amdgcn_sched_barrier(0);
    MFMA_PH(1, a1);

    ISSUE_A(a1, At, 3);
    asm volatile("s_waitcnt lgkmcnt(4)" ::: "memory");  // a0 ready; a1(ph3) in flight
    __builtin_amdgcn_sched_barrier(0);
    MFMA_PH(2, a0);

    asm volatile("s_waitcnt lgkmcnt(0)" ::: "memory");  // a1 ready
    __builtin_amdgcn_sched_barrier(0);
    MFMA_PH(3, a1);

    // tile seam: next slot must be fully staged; keep kt+2's loads in flight
    if (kt < 14) {
      asm volatile("s_waitcnt vmcnt(4)" ::: "memory");
    } else if (kt == 14) {
      asm volatile("s_waitcnt vmcnt(0)" ::: "memory");
    }
    __builtin_amdgcn_sched_barrier(0);
    __builtin_amdgcn_s_barrier();  // bounds wave skew; c2 safe to restage next tile

    int tmp = c0; c0 = c1; c1 = c2; c2 = tmp;
  }
#undef MFMA_PH
#undef LOAD_B
#undef STAGE4
#undef ISSUE_A

  // epilogue: C/D layout col=lane&15, row=(lane>>4)*4+reg
  float* outB = out + ((size_t)b * NS + m0) * ND + n0;
#pragma unroll
  for (int i = 0; i < 8; ++i) {
#pragma unroll
    for (int rg = 0; rg < 4; ++rg) {
      int r = i * 16 + q * 4 + rg;
      float* orow = outB + (size_t)r * ND + wn * 64 + l16;
#pragma unroll
      for (int n = 0; n < 4; ++n)
        orow[n * 16] = acc[i][n][rg];
    }
  }
}

// ---------- fallback path (round-1 kernels) in case ws is small ----------
__global__ void anorm_kernel(const float* __restrict__ aspect,
                             unsigned short* __restrict__ a_n) {
  int b = blockIdx.x;
  int t = threadIdx.x;
  const float4* p = (const float4*)(aspect + (size_t)b * ND);
  float4 v = p[t];
  float s = v.x * v.x + v.y * v.y + v.z * v.z + v.w * v.w;
#pragma unroll
  for (int off = 32; off >= 1; off >>= 1) s += __shfl_down(s, off);
  __shared__ float red[4];
  if ((t & 63) == 0) red[t >> 6] = s;
  __syncthreads();
  float tot = red[0] + red[1] + red[2] + red[3];
  float inv = (tot > 0.f) ? (1.f / sqrtf(tot)) : 0.f;
  ushort4 u;
  u.x = f2bf(v.x * inv); u.y = f2bf(v.y * inv);
  u.z = f2bf(v.z * inv); u.w = f2bf(v.w * inv);
  ((ushort4*)(a_n + (size_t)b * ND))[t] = u;
}

__global__ void enorm_kernel(const float* __restrict__ emb,
                             float* __restrict__ inv_norm) {
  int wave = threadIdx.x >> 6;
  int lane = threadIdx.x & 63;
  int row = blockIdx.x * 4 + wave;
  const float4* p = (const float4*)(emb + (size_t)row * ND);
  float s = 0.f;
#pragma unroll
  for (int j = 0; j < 4; ++j) {
    float4 v = p[lane + 64 * j];
    s += v.x * v.x + v.y * v.y + v.z * v.z + v.w * v.w;
  }
#pragma unroll
  for (int off = 32; off >= 1; off >>= 1) s += __shfl_down(s, off);
  if (lane == 0) inv_norm[row] = (s > 0.f) ? (1.f / sqrtf(s)) : 0.f;
}

__global__ __launch_bounds__(256)
void corr_gemm_kernel(const float* __restrict__ emb,
                      const float* __restrict__ inv_norm,
                      const unsigned short* __restrict__ a_n,
                      float* __restrict__ out) {
  __shared__ unsigned short copies[8][2056];
  __shared__ unsigned short Atile[128][40];

  const int nt = blockIdx.x, mt = blockIdx.y, b = blockIdx.z;
  const int n0 = nt * 128, m0 = mt * 128;
  const int t = threadIdx.x;

  {
    const unsigned short* an = a_n + (size_t)b * ND;
    int p = t & 7;
    int x0 = (t >> 3) * 64;
#pragma unroll
    for (int j = 0; j < 64; j += 4) {
      ushort4 u;
      u.x = an[(x0 + j + 0 + p) & 1023];
      u.y = an[(x0 + j + 1 + p) & 1023];
      u.z = an[(x0 + j + 2 + p) & 1023];
      u.w = an[(x0 + j + 3 + p) & 1023];
      *(ushort4*)&copies[p][x0 + j] = u;
    }
  }

  const int ar = t >> 3;
  const int ac = (t & 7) * 4;
  float invn[4];
#pragma unroll
  for (int w = 0; w < 4; ++w)
    invn[w] = inv_norm[b * NS + m0 + ar + 32 * w];

  const int lane = t & 63;
  const int wv = t >> 6;
  const int wm = wv >> 1, wn = wv & 1;
  const int q = lane >> 4, l16 = lane & 15;

  f32x4 acc[4][4];
#pragma unroll
  for (int i = 0; i < 4; ++i)
#pragma unroll
    for (int j = 0; j < 4; ++j)
      acc[i][j] = (f32x4){0.f, 0.f, 0.f, 0.f};

  const float* embB = emb + ((size_t)b * NS + m0) * ND;

  for (int k0 = 0; k0 < ND; k0 += 32) {
    __syncthreads();
#pragma unroll
    for (int w = 0; w < 4; ++w) {
      int r = ar + 32 * w;
      float4 v = *(const float4*)(embB + (size_t)r * ND + k0 + ac);
      float in = invn[w];
      ushort4 u;
      u.x = f2bf(v.x * in); u.y = f2bf(v.y * in);
      u.z = f2bf(v.z * in); u.w = f2bf(v.w * in);
      *(ushort4*)&Atile[r][ac] = u;
    }
    __syncthreads();

    bf16x8 af[4], bfr[4];
#pragma unroll
    for (int r = 0; r < 4; ++r) {
      int m = wm * 64 + r * 16 + l16;
      af[r] = *(const bf16x8*)&Atile[m][q * 8];
    }
#pragma unroll
    for (int r = 0; r < 4; ++r) {
      int ng = n0 + wn * 64 + r * 16 + l16;
      int e0 = k0 + 8 * q - ng + 1024;
      int p = e0 & 7;
      bfr[r] = *(const bf16x8*)&copies[p][e0 - p];
    }
#pragma unroll
    for (int i = 0; i < 4; ++i)
#pragma unroll
      for (int j = 0; j < 4; ++j)
        acc[i][j] = __builtin_amdgcn_mfma_f32_16x16x32_bf16(af[i], bfr[j], acc[i][j], 0, 0, 0);
  }

  float* outB = out + ((size_t)b * NS + m0) * ND + n0;
#pragma unroll
  for (int i = 0; i < 4; ++i) {
#pragma unroll
    for (int rg = 0; rg < 4; ++rg) {
      int s = wm * 64 + i * 16 + q * 4 + rg;
      float* orow = outB + (size_t)s * ND + wn * 64 + l16;
#pragma unroll
      for (int j = 0; j < 4; ++j)
        orow[j * 16] = acc[i][j][rg];
    }
  }
}

extern "C" void kernel_launch(void* const* d_in, const int* in_sizes, int n_in,
                              void* d_out, int out_size, void* d_ws, size_t ws_size,
                              hipStream_t stream) {
  const float* emb = (const float*)d_in[0];
  const float* aspect = (const float*)d_in[1];
  float* out = (float*)d_out;

  const size_t need = 65536 + (size_t)NB * NS * ND * 2;  // a_n + eN(bf16)

  if (ws_size >= need) {
    unsigned short* a_n = (unsigned short*)d_ws;
    unsigned short* eN = (unsigned short*)((char*)d_ws + 65536);
    enormbf_fused_kernel<<<4096, 256, 0, stream>>>(emb, eN, aspect, a_n);
    // grid (b, mt, nt): flat id = b + 32*(mt + 4*nt) -> XCD = b%8; all 16 tiles
    // of batch b share an XCD -> eN panel L2 reuse across mt/nt siblings.
    corr_gemm8_kernel<<<dim3(NB, 4, 4), 256, 0, stream>>>(eN, a_n, out);
  } else {
    float* inv_norm = (float*)d_ws;
    unsigned short* a_n = (unsigned short*)((char*)d_ws + 65536);
    enorm_kernel<<<4096, 256, 0, stream>>>(emb, inv_norm);
    anorm_kernel<<<NB, 256, 0, stream>>>(aspect, a_n);
    corr_gemm_kernel<<<dim3(8, 4, NB), 256, 0, stream>>>(emb, inv_norm, a_n, out);
  }
}